// Round 6
// baseline (103.071 us; speedup 1.0000x reference)
//
#include <hip/hip_runtime.h>
#include <math.h>

// Problem constants
#define NB    32
#define NHEAD 16
#define HW    1024

typedef float f32x4  __attribute__((ext_vector_type(4)));
typedef short bf16x2 __attribute__((ext_vector_type(2)));
typedef short bf16x4 __attribute__((ext_vector_type(4)));
typedef short bf16x8 __attribute__((ext_vector_type(8)));

__device__ __forceinline__ short f2bf(float f) {   // fp32 -> bf16 RNE
    union { float f; unsigned u; } c; c.f = f;
    unsigned r = c.u + 0x7FFFu + ((c.u >> 16) & 1u);
    return (short)(r >> 16);
}
#define SWZ(row) ((((row) >> 1) & 7) << 4)
#define MFMA16(a, b, c) __builtin_amdgcn_mfma_f32_16x16x32_bf16(a, b, c, 0, 0, 0)

__device__ __forceinline__ bf16x8 lds_ld8(const short* base, int off) {
    return *(const bf16x8*)((const char*)base + off);
}
__device__ __forceinline__ void lds_st4(short* base, int off, bf16x4 v) {
    *(bf16x4*)((char*)base + off) = v;
}

// ---------------------------------------------------------------------------
// Kernel 0: prep — bf16 casts / transposes / bias fold. (unchanged, passes)
// ---------------------------------------------------------------------------
__global__ __launch_bounds__(256) void prep_kernel(
        const float* __restrict__ Wq, const float* __restrict__ token,
        const float* __restrict__ Wk, const float* __restrict__ bq,
        short* __restrict__ Wq_bf, short* __restrict__ tok_t,
        short* __restrict__ Wk_t, float* __restrict__ qkb) {
    __shared__ float red[256];
    const int b = blockIdx.x, t = threadIdx.x;
    if (b < 1024) {
        const size_t idx = (size_t)b * 1024 + t * 4;
        const f32x4 v = *(const f32x4*)(Wq + idx);
        bf16x4 o; o[0]=f2bf(v[0]); o[1]=f2bf(v[1]); o[2]=f2bf(v[2]); o[3]=f2bf(v[3]);
        *(bf16x4*)(Wq_bf + idx) = o;
    } else if (b < 1056) {
        const int n = b - 1024;
        const int c0 = t * 4;
        float arr[4][16];
#pragma unroll
        for (int ci = 0; ci < 4; ++ci)
#pragma unroll
            for (int lq = 0; lq < 4; ++lq) {
                const f32x4 v = *(const f32x4*)(token + (size_t)n*16384 + (size_t)(c0+ci)*16 + lq*4);
#pragma unroll
                for (int e = 0; e < 4; ++e) arr[ci][lq*4+e] = v[e];
            }
#pragma unroll
        for (int l = 0; l < 16; ++l) {
            bf16x4 o; o[0]=f2bf(arr[0][l]); o[1]=f2bf(arr[1][l]); o[2]=f2bf(arr[2][l]); o[3]=f2bf(arr[3][l]);
            *(bf16x4*)(tok_t + (size_t)n*16384 + (size_t)l*1024 + c0) = o;
        }
    } else {
        const int h = b - 1056;
        const int i = t & 63, dq = t >> 6;
        float qs = 0.f; short wt[16];
#pragma unroll
        for (int k = 0; k < 16; ++k) {
            const int d = dq*16 + k;
            const float wv = Wk[(size_t)h*4096 + d*64 + i];
            qs += wv * bq[h*64 + d];
            wt[k] = f2bf(wv);
        }
#pragma unroll
        for (int kq = 0; kq < 4; ++kq) {
            bf16x4 o; o[0]=wt[kq*4]; o[1]=wt[kq*4+1]; o[2]=wt[kq*4+2]; o[3]=wt[kq*4+3];
            *(bf16x4*)(Wk_t + (size_t)h*4096 + i*64 + dq*16 + kq*4) = o;
        }
        red[t] = qs;
        __syncthreads();
        if (t < 64)
            qkb[h*64 + t] = (red[t] + red[t+64] + red[t+128] + red[t+192]) * 0.125f;
    }
}

// ---------------------------------------------------------------------------
// Kernel 1: fused query + qk (all-MFMA). (unchanged, passes)
// ---------------------------------------------------------------------------
__global__ __launch_bounds__(256) void queryqk_kernel(
        const short* __restrict__ Wq_bf, const short* __restrict__ tok_t,
        const short* __restrict__ Wk_t, const float* __restrict__ qkb,
        short* __restrict__ qk_bf) {
    __shared__ short q_ld[16 * 64];
    const int t = threadIdx.x, w = t >> 6, L = t & 63;
    const int lr = L & 15, hg = L >> 4;
    const int nh = blockIdx.x, n = nh >> 4, h = nh & 15;

    f32x4 acc = {0.f, 0.f, 0.f, 0.f};
    const short* aA = Wq_bf + (size_t)(h*64 + w*16 + lr) * 1024 + hg*8;
    const short* aB = tok_t + (size_t)n*16384 + (size_t)lr*1024 + hg*8;
#pragma unroll 4
    for (int ks = 0; ks < 32; ++ks) {
        const bf16x8 a = *(const bf16x8*)(aA + ks*32);
        const bf16x8 bb = *(const bf16x8*)(aB + ks*32);
        acc = MFMA16(a, bb, acc);
    }
    {
        bf16x4 qv; qv[0]=f2bf(acc[0]); qv[1]=f2bf(acc[1]); qv[2]=f2bf(acc[2]); qv[3]=f2bf(acc[3]);
        lds_st4(q_ld, (lr*128 + w*32 + hg*8) ^ SWZ(lr), qv);
    }
    __syncthreads();
    f32x4 a2 = {0.f, 0.f, 0.f, 0.f};
#pragma unroll
    for (int ks = 0; ks < 2; ++ks) {
        const bf16x8 a = *(const bf16x8*)(Wk_t + (size_t)h*4096 + (w*16 + lr)*64 + ks*32 + hg*8);
        const bf16x8 bb = lds_ld8(q_ld, (lr*128 + ks*64 + hg*16) ^ SWZ(lr));
        a2 = MFMA16(a, bb, a2);
    }
    const int i0 = w*16 + hg*4;
    bf16x4 qk4;
#pragma unroll
    for (int r = 0; r < 4; ++r)
        qk4[r] = f2bf(a2[r] * 0.125f + qkb[h*64 + i0 + r]);
    *(bf16x4*)(qk_bf + (size_t)nh*1024 + lr*64 + i0) = qk4;
}

// ---------------------------------------------------------------------------
// Kernel 2: whole-slab attention, 76 KB LDS -> 2 blocks/CU co-resident so one
// block's staging overlaps the other's compute (R5 was 143 KB = 1 block/CU and
// the memory pipe idled through every compute phase: 2.9 TB/s).
//   pass 1: 2 chunks x 32 rows: stage (fused out0 copy) -> logits MFMA (S regs)
//   softmax in regs; P transposed to B-frags via 2KB/wave scratch (reuse f_stage)
//   pass 2: re-read slab (L2-hot), fc += MFMA, acc in REGISTERS
//   epilogue: fc reduce via f_stage, normalize, tok = Wv @ fcn + bv -> out1
// ---------------------------------------------------------------------------
__global__ __launch_bounds__(1024, 8) void attn_kernel(
        const float* __restrict__ feat, const short* __restrict__ qk_bf,
        const float* __restrict__ Wv, const float* __restrict__ bv,
        float* __restrict__ out0, float* __restrict__ out1) {
    __shared__ __align__(16) short f_stage[32 * 1024];  // 64 KB, multi-purpose
    __shared__ __align__(16) short wv_ld[64 * 64];      // 8 KB [d][i] bf16 swz
    __shared__ __align__(16) short fcn_ld[16 * 64];     // 2 KB [l][i] bf16 swz
    __shared__ float red_m[256], red_z[256];            // 2 KB

    const int t = threadIdx.x, w = t >> 6, L = t & 63;
    const int lr = L & 15, hg = L >> 4;
    const int nh = blockIdx.x, n = nh >> 4, h = nh & 15;
    const size_t fbase = (size_t)n*1048576 + (size_t)h*65536;

    // qk B-fragments (L2-hot); dead after pass 1
    const bf16x8 qb0 = *(const bf16x8*)(qk_bf + (size_t)nh*1024 + lr*64 + hg*8);
    const bf16x8 qb1 = *(const bf16x8*)(qk_bf + (size_t)nh*1024 + lr*64 + 32 + hg*8);

    f32x4 S[4];
#pragma unroll
    for (int tl = 0; tl < 4; ++tl) S[tl] = (f32x4){0.f, 0.f, 0.f, 0.f};

    // ================= pass 1: logits =================
    for (int c = 0; c < 2; ++c) {
        {   // stage rows {c*32+w*2, +1}: sequential 1KB/instr loads, fused copy
            const size_t rbase = fbase + (size_t)(c*32 + w*2) * 1024;
#pragma unroll
            for (int xr = 0; xr < 4; ++xr) {
                const int x0 = xr*256 + L*4;
                const f32x4 v0 = *(const f32x4*)(feat + rbase + x0);
                const f32x4 v1 = *(const f32x4*)(feat + rbase + 1024 + x0);
                *(f32x4*)(out0 + rbase + x0) = v0;
                *(f32x4*)(out0 + rbase + 1024 + x0) = v1;
#pragma unroll
                for (int j = 0; j < 4; ++j) {   // transposed: f_xi[x][i-pair]
                    const int x = x0 + j;
                    bf16x2 pr; pr[0] = f2bf(v0[j]); pr[1] = f2bf(v1[j]);
                    const int off = ((x>>1)<<7) + ((((x&1)<<6) + w*4) ^ (((x>>2)&7)<<4));
                    *(bf16x2*)((char*)f_stage + off) = pr;
                }
            }
        }
        __syncthreads();
        {   // logits MFMA: wave's x-slab = [w*64, +64), K = chunk's 32 i
            const bf16x8 qb = c ? qb1 : qb0;
#pragma unroll
            for (int tl = 0; tl < 4; ++tl) {
                const int x = w*64 + tl*16 + lr;
                const int off = ((x>>1)<<7) + ((((x&1)<<6) + (hg<<4)) ^ (((x>>2)&7)<<4));
                const bf16x8 a = *(const bf16x8*)((const char*)f_stage + off);
                S[tl] = MFMA16(a, qb, S[tl]);
            }
        }
        __syncthreads();
    }

    // ================= softmax (P stays in registers) =================
    float m_l = -INFINITY;
#pragma unroll
    for (int tl = 0; tl < 4; ++tl)
#pragma unroll
        for (int r = 0; r < 4; ++r) m_l = fmaxf(m_l, S[tl][r]);
    m_l = fmaxf(m_l, __shfl_xor(m_l, 16));
    m_l = fmaxf(m_l, __shfl_xor(m_l, 32));
    if (L < 16) red_m[w*16 + L] = m_l;
    __syncthreads();
    float m_g = -INFINITY;
#pragma unroll
    for (int k = 0; k < 16; ++k) m_g = fmaxf(m_g, red_m[k*16 + lr]);
    float zl = 0.f;
#pragma unroll
    for (int tl = 0; tl < 4; ++tl)
#pragma unroll
        for (int r = 0; r < 4; ++r) {
            S[tl][r] = __expf(S[tl][r] - m_g);
            zl += S[tl][r];
        }
    // P -> per-wave 2KB scratch [l][x_local] (reuse f_stage; pass-1 data dead)
#pragma unroll
    for (int tl = 0; tl < 4; ++tl) {
        bf16x4 pv; pv[0]=f2bf(S[tl][0]); pv[1]=f2bf(S[tl][1]); pv[2]=f2bf(S[tl][2]); pv[3]=f2bf(S[tl][3]);
        *(bf16x4*)((char*)f_stage + w*2048 + lr*128 + (((tl*32 + hg*8)) ^ ((lr&7)<<4))) = pv;
    }
    zl += __shfl_xor(zl, 16);
    zl += __shfl_xor(zl, 32);
    if (L < 16) red_z[w*16 + L] = zl;
    __syncthreads();
    float Zg = 0.f;
#pragma unroll
    for (int k = 0; k < 16; ++k) Zg += red_z[k*16 + lr];
    const float rz = 1.f / Zg;
    // read back as B-frags: pb[ks] covers k = x_local ks*32..+32, col = l
    const bf16x8 pb0 = *(const bf16x8*)((const char*)f_stage + w*2048 + lr*128 + ((      hg*16) ^ ((lr&7)<<4)));
    const bf16x8 pb1 = *(const bf16x8*)((const char*)f_stage + w*2048 + lr*128 + ((64 + hg*16) ^ ((lr&7)<<4)));
    __syncthreads();   // pb reads done before pass-2 staging overwrites

    // ================= pass 2: fc += f @ P (acc in regs) =================
    f32x4 acc_fc[4];
#pragma unroll
    for (int ct = 0; ct < 4; ++ct) acc_fc[ct] = (f32x4){0.f, 0.f, 0.f, 0.f};
    for (int c = 0; c < 2; ++c) {
        {   // stage natural f_ix[i32][x] (re-read: L2-hot)
            const size_t rbase = fbase + (size_t)(c*32 + w*2) * 1024;
            const int il0 = w*2, il1 = w*2 + 1;
#pragma unroll
            for (int xr = 0; xr < 4; ++xr) {
                const int x0 = xr*256 + L*4;
                const f32x4 v0 = *(const f32x4*)(feat + rbase + x0);
                const f32x4 v1 = *(const f32x4*)(feat + rbase + 1024 + x0);
                bf16x4 b0; b0[0]=f2bf(v0[0]); b0[1]=f2bf(v0[1]); b0[2]=f2bf(v0[2]); b0[3]=f2bf(v0[3]);
                bf16x4 b1; b1[0]=f2bf(v1[0]); b1[1]=f2bf(v1[1]); b1[2]=f2bf(v1[2]); b1[3]=f2bf(v1[3]);
                *(bf16x4*)((char*)f_stage + il0*2048 + ((x0*2) ^ ((il0&7)<<4))) = b0;
                *(bf16x4*)((char*)f_stage + il1*2048 + ((x0*2) ^ ((il1&7)<<4))) = b1;
            }
        }
        __syncthreads();
        {   // fc MFMA: 2 i-tiles x (K=64 over wave's own x-slab = 2 K-steps)
#pragma unroll
            for (int tl2 = 0; tl2 < 2; ++tl2) {
                const int il_m = tl2*16 + lr;
                const int base = il_m*2048, swz = (il_m&7)<<4;
                const int ct = c*2 + tl2;
                acc_fc[ct] = MFMA16(lds_ld8(f_stage, base + ((w*128      + hg*16) ^ swz)), pb0, acc_fc[ct]);
                acc_fc[ct] = MFMA16(lds_ld8(f_stage, base + ((w*128 + 64 + hg*16) ^ swz)), pb1, acc_fc[ct]);
            }
        }
        __syncthreads();
    }

    // ================= reduce + normalize + epilogue =================
#pragma unroll
    for (int ct = 0; ct < 4; ++ct)   // f_stage reused as f32x4 [w][tile][lane]
        *(f32x4*)((char*)f_stage + w*4096 + ct*1024 + L*16) = acc_fc[ct];
    {   // Wv -> LDS [d][i] bf16
        const int d = t >> 4, i4 = (t & 15) * 4;
        const f32x4 wv4 = *(const f32x4*)(Wv + (size_t)h*4096 + d*64 + i4);
        bf16x4 wb; wb[0]=f2bf(wv4[0]); wb[1]=f2bf(wv4[1]); wb[2]=f2bf(wv4[2]); wb[3]=f2bf(wv4[3]);
        *(bf16x4*)((char*)wv_ld + d*128 + ((i4*2) ^ ((d&7)<<4))) = wb;
    }
    __syncthreads();
    if (w < 4) {   // wave w reduces i-tile w over 16 wave-partials
        f32x4 sum = (f32x4){0.f, 0.f, 0.f, 0.f};
#pragma unroll
        for (int wp = 0; wp < 16; ++wp)
            sum += *(const f32x4*)((const char*)f_stage + wp*4096 + w*1024 + L*16);
        bf16x4 fb;
#pragma unroll
        for (int r = 0; r < 4; ++r) fb[r] = f2bf(sum[r] * rz);
        *(bf16x4*)((char*)fcn_ld + lr*128 + ((w*32 + hg*8) ^ ((lr&7)<<4))) = fb;
    }
    __syncthreads();
    if (w < 4) {   // tok[d][l] = Wv @ fcn + bv; wave w owns d-tile w
        f32x4 acc = (f32x4){0.f, 0.f, 0.f, 0.f};
        const int d_m = w*16 + lr;
#pragma unroll
        for (int ks = 0; ks < 2; ++ks) {
            const bf16x8 a = lds_ld8(wv_ld, d_m*128 + ((ks*64 + hg*16) ^ ((d_m&7)<<4)));
            const bf16x8 b = lds_ld8(fcn_ld, lr*128 + ((ks*64 + hg*16) ^ ((lr&7)<<4)));
            acc = MFMA16(a, b, acc);
        }
#pragma unroll
        for (int r = 0; r < 4; ++r) {
            const int d = w*16 + hg*4 + r;
            out1[((size_t)n*1024 + h*64 + d)*16 + lr] = acc[r] + bv[h*64 + d];
        }
    }
}

// ---------------------------------------------------------------------------
extern "C" void kernel_launch(void* const* d_in, const int* in_sizes, int n_in,
                              void* d_out, int out_size, void* d_ws, size_t ws_size,
                              hipStream_t stream) {
    const float* feature = (const float*)d_in[0];
    const float* token   = (const float*)d_in[1];
    const float* Wq      = (const float*)d_in[2];
    const float* bq      = (const float*)d_in[3];
    const float* Wk      = (const float*)d_in[4];
    // d_in[5] = bk: provably unused (constant along softmax axis)
    const float* Wv      = (const float*)d_in[6];
    const float* bv      = (const float*)d_in[7];

    float* out0 = (float*)d_out;                      // feature passthrough
    float* out1 = out0 + (size_t)NB * 1024 * HW;      // tok [n][c][l]

    short* Wq_bf = (short*)d_ws;                               // 2 MB
    short* tok_t = Wq_bf + (size_t)1024 * 1024;                // 1 MB
    short* Wk_t  = tok_t + (size_t)NB * 16 * 1024;             // 128 KB
    short* qk_bf = Wk_t + (size_t)NHEAD * 64 * 64;             // 1 MB
    float* qkb   = (float*)(qk_bf + (size_t)NB * NHEAD * 1024);// 4 KB

    prep_kernel   <<<dim3(1072), 256, 0, stream>>>(Wq, token, Wk, bq, Wq_bf, tok_t, Wk_t, qkb);
    queryqk_kernel<<<dim3(NB * NHEAD), 256, 0, stream>>>(Wq_bf, tok_t, Wk_t, qkb, qk_bf);
    attn_kernel   <<<dim3(NB * NHEAD), 1024, 0, stream>>>(feature, qk_bf, Wv, bv, out0, out1);
}

// Round 7
// 75.727 us; speedup vs baseline: 1.3611x; 1.3611x over previous
//
#include <hip/hip_runtime.h>
#include <math.h>

// Problem constants
#define NB    32
#define NHEAD 16
#define HW    1024

typedef float f32x4  __attribute__((ext_vector_type(4)));
typedef short bf16x2 __attribute__((ext_vector_type(2)));
typedef short bf16x4 __attribute__((ext_vector_type(4)));
typedef short bf16x8 __attribute__((ext_vector_type(8)));

__device__ __forceinline__ short f2bf(float f) {   // fp32 -> bf16 RNE
    union { float f; unsigned u; } c; c.f = f;
    unsigned r = c.u + 0x7FFFu + ((c.u >> 16) & 1u);
    return (short)(r >> 16);
}
#define SWZ(row) ((((row) >> 1) & 7) << 4)
#define MFMA16(a, b, c) __builtin_amdgcn_mfma_f32_16x16x32_bf16(a, b, c, 0, 0, 0)

__device__ __forceinline__ bf16x8 lds_ld8(const short* base, int off) {
    return *(const bf16x8*)((const char*)base + off);
}
__device__ __forceinline__ void lds_st4(short* base, int off, bf16x4 v) {
    *(bf16x4*)((char*)base + off) = v;
}

// ---------------------------------------------------------------------------
// Kernel 0: prep — bf16 casts / transposes / bias fold. (unchanged, passes)
// ---------------------------------------------------------------------------
__global__ __launch_bounds__(256) void prep_kernel(
        const float* __restrict__ Wq, const float* __restrict__ token,
        const float* __restrict__ Wk, const float* __restrict__ bq,
        short* __restrict__ Wq_bf, short* __restrict__ tok_t,
        short* __restrict__ Wk_t, float* __restrict__ qkb) {
    __shared__ float red[256];
    const int b = blockIdx.x, t = threadIdx.x;
    if (b < 1024) {
        const size_t idx = (size_t)b * 1024 + t * 4;
        const f32x4 v = *(const f32x4*)(Wq + idx);
        bf16x4 o; o[0]=f2bf(v[0]); o[1]=f2bf(v[1]); o[2]=f2bf(v[2]); o[3]=f2bf(v[3]);
        *(bf16x4*)(Wq_bf + idx) = o;
    } else if (b < 1056) {
        const int n = b - 1024;
        const int c0 = t * 4;
        float arr[4][16];
#pragma unroll
        for (int ci = 0; ci < 4; ++ci)
#pragma unroll
            for (int lq = 0; lq < 4; ++lq) {
                const f32x4 v = *(const f32x4*)(token + (size_t)n*16384 + (size_t)(c0+ci)*16 + lq*4);
#pragma unroll
                for (int e = 0; e < 4; ++e) arr[ci][lq*4+e] = v[e];
            }
#pragma unroll
        for (int l = 0; l < 16; ++l) {
            bf16x4 o; o[0]=f2bf(arr[0][l]); o[1]=f2bf(arr[1][l]); o[2]=f2bf(arr[2][l]); o[3]=f2bf(arr[3][l]);
            *(bf16x4*)(tok_t + (size_t)n*16384 + (size_t)l*1024 + c0) = o;
        }
    } else {
        const int h = b - 1056;
        const int i = t & 63, dq = t >> 6;
        float qs = 0.f; short wt[16];
#pragma unroll
        for (int k = 0; k < 16; ++k) {
            const int d = dq*16 + k;
            const float wv = Wk[(size_t)h*4096 + d*64 + i];
            qs += wv * bq[h*64 + d];
            wt[k] = f2bf(wv);
        }
#pragma unroll
        for (int kq = 0; kq < 4; ++kq) {
            bf16x4 o; o[0]=wt[kq*4]; o[1]=wt[kq*4+1]; o[2]=wt[kq*4+2]; o[3]=wt[kq*4+3];
            *(bf16x4*)(Wk_t + (size_t)h*4096 + i*64 + dq*16 + kq*4) = o;
        }
        red[t] = qs;
        __syncthreads();
        if (t < 64)
            qkb[h*64 + t] = (red[t] + red[t+64] + red[t+128] + red[t+192]) * 0.125f;
    }
}

// ---------------------------------------------------------------------------
// Kernel 1: fused query + qk (all-MFMA). (unchanged, passes)
// ---------------------------------------------------------------------------
__global__ __launch_bounds__(256) void queryqk_kernel(
        const short* __restrict__ Wq_bf, const short* __restrict__ tok_t,
        const short* __restrict__ Wk_t, const float* __restrict__ qkb,
        short* __restrict__ qk_bf) {
    __shared__ short q_ld[16 * 64];
    const int t = threadIdx.x, w = t >> 6, L = t & 63;
    const int lr = L & 15, hg = L >> 4;
    const int nh = blockIdx.x, n = nh >> 4, h = nh & 15;

    f32x4 acc = {0.f, 0.f, 0.f, 0.f};
    const short* aA = Wq_bf + (size_t)(h*64 + w*16 + lr) * 1024 + hg*8;
    const short* aB = tok_t + (size_t)n*16384 + (size_t)lr*1024 + hg*8;
#pragma unroll 4
    for (int ks = 0; ks < 32; ++ks) {
        const bf16x8 a = *(const bf16x8*)(aA + ks*32);
        const bf16x8 bb = *(const bf16x8*)(aB + ks*32);
        acc = MFMA16(a, bb, acc);
    }
    {
        bf16x4 qv; qv[0]=f2bf(acc[0]); qv[1]=f2bf(acc[1]); qv[2]=f2bf(acc[2]); qv[3]=f2bf(acc[3]);
        lds_st4(q_ld, (lr*128 + w*32 + hg*8) ^ SWZ(lr), qv);
    }
    __syncthreads();
    f32x4 a2 = {0.f, 0.f, 0.f, 0.f};
#pragma unroll
    for (int ks = 0; ks < 2; ++ks) {
        const bf16x8 a = *(const bf16x8*)(Wk_t + (size_t)h*4096 + (w*16 + lr)*64 + ks*32 + hg*8);
        const bf16x8 bb = lds_ld8(q_ld, (lr*128 + ks*64 + hg*16) ^ SWZ(lr));
        a2 = MFMA16(a, bb, a2);
    }
    const int i0 = w*16 + hg*4;
    bf16x4 qk4;
#pragma unroll
    for (int r = 0; r < 4; ++r)
        qk4[r] = f2bf(a2[r] * 0.125f + qkb[h*64 + i0 + r]);
    *(bf16x4*)(qk_bf + (size_t)nh*1024 + lr*64 + i0) = qk4;
}

// ---------------------------------------------------------------------------
// Kernel 2: SINGLE-PASS whole-slab attention. One block per (n,h), 16 waves.
//   launch_bounds(1024,4): 128 VGPR cap — NO spills (R6's (1024,8) forced
//   VGPR=32 and spilled ~50 live floats to scratch; got slower).
//   Per 32-channel chunk: write prefetched regs -> f_xi (logits layout) AND
//   f_ix ([i][x] layout) + out0 copy; prefetch next chunk; barrier;
//   logits MFMA + extract fc A-frags into REGISTERS (kills R5/R6's pass-2
//   134 MB re-read). Then softmax, fc from regs, reduce, Wv epilogue.
//   Vector traffic: 268 MB (was 402 MB).
// ---------------------------------------------------------------------------
__global__ __launch_bounds__(1024, 4) void attn_kernel(
        const float* __restrict__ feat, const short* __restrict__ qk_bf,
        const float* __restrict__ Wv, const float* __restrict__ bv,
        float* __restrict__ out0, float* __restrict__ out1) {
    __shared__ __align__(16) short f_xi[32 * 1024];   // 64 KB logits layout; reused: P-scratch
    __shared__ __align__(16) short f_ix[32 * 1024];   // 64 KB [i][x] layout; reused: acc dump
    __shared__ __align__(16) short wv_ld[64 * 64];    // 8 KB [d][i] bf16 swz
    __shared__ __align__(16) short fcn_ld[16 * 64];   // 2 KB [l][i] bf16 swz
    __shared__ float red_m[256], red_z[256];          // 2 KB

    const int t = threadIdx.x, w = t >> 6, L = t & 63;
    const int lr = L & 15, hg = L >> 4;
    const int nh = blockIdx.x, n = nh >> 4, h = nh & 15;
    const size_t fbase = (size_t)n*1048576 + (size_t)h*65536;

    // prologue: small operand loads + chunk-0 prefetch
    const bf16x8 qb0 = *(const bf16x8*)(qk_bf + (size_t)nh*1024 + lr*64 + hg*8);
    const bf16x8 qb1 = *(const bf16x8*)(qk_bf + (size_t)nh*1024 + lr*64 + 32 + hg*8);
    const f32x4 wv4 = *(const f32x4*)(Wv + (size_t)h*4096 + (t>>4)*64 + (t&15)*4);

    f32x4 v[8];   // rows {c*32+w*2, +1} x 4 x-segments (static-indexed only)
    {
        const size_t rb = fbase + (size_t)(w*2) * 1024;
#pragma unroll
        for (int xr = 0; xr < 4; ++xr) {
            v[2*xr]   = *(const f32x4*)(feat + rb + xr*256 + L*4);
            v[2*xr+1] = *(const f32x4*)(feat + rb + 1024 + xr*256 + L*4);
        }
    }

    f32x4 S[4];
#pragma unroll
    for (int tl = 0; tl < 4; ++tl) S[tl] = (f32x4){0.f, 0.f, 0.f, 0.f};
    bf16x8 fcA[4][2];

#pragma unroll
    for (int c = 0; c < 2; ++c) {
        // ---- phase A: drain regs to LDS (both layouts) + out0; prefetch next ----
        {
            const size_t rb = fbase + (size_t)(c*32 + w*2) * 1024;
            const int il0 = w*2, il1 = w*2 + 1;
#pragma unroll
            for (int xr = 0; xr < 4; ++xr) {
                const int x0 = xr*256 + L*4;
                const f32x4 v0 = v[2*xr], v1 = v[2*xr+1];
                *(f32x4*)(out0 + rb + x0) = v0;
                *(f32x4*)(out0 + rb + 1024 + x0) = v1;
                // f_ix[i][x]: 4 consecutive x per row
                bf16x4 b0; b0[0]=f2bf(v0[0]); b0[1]=f2bf(v0[1]); b0[2]=f2bf(v0[2]); b0[3]=f2bf(v0[3]);
                bf16x4 b1; b1[0]=f2bf(v1[0]); b1[1]=f2bf(v1[1]); b1[2]=f2bf(v1[2]); b1[3]=f2bf(v1[3]);
                lds_st4(f_ix, il0*2048 + ((x0*2) ^ ((il0&7)<<4)), b0);
                lds_st4(f_ix, il1*2048 + ((x0*2) ^ ((il1&7)<<4)), b1);
                // f_xi[x][ch-pair w]: channel pair packed per x
#pragma unroll
                for (int j = 0; j < 4; ++j) {
                    const int x = x0 + j;
                    bf16x2 pr; pr[0] = f2bf(v0[j]); pr[1] = f2bf(v1[j]);
                    const int off = ((x>>1)<<7) + ((((x&1)<<6) + w*4) ^ (((x>>2)&7)<<4));
                    *(bf16x2*)((char*)f_xi + off) = pr;
                }
            }
            if (c == 0) {   // prefetch chunk 1 (T14: issue-early, consume next phase)
                const size_t rb1 = fbase + (size_t)(32 + w*2) * 1024;
#pragma unroll
                for (int xr = 0; xr < 4; ++xr) {
                    v[2*xr]   = *(const f32x4*)(feat + rb1 + xr*256 + L*4);
                    v[2*xr+1] = *(const f32x4*)(feat + rb1 + 1024 + xr*256 + L*4);
                }
            }
        }
        __syncthreads();
        // ---- phase B: logits MFMA + extract fc A-frags to registers ----
        {
            const bf16x8 qb = c ? qb1 : qb0;
#pragma unroll
            for (int tl = 0; tl < 4; ++tl) {
                const int x = w*64 + tl*16 + lr;
                const int off = ((x>>1)<<7) + ((((x&1)<<6) + (hg<<4)) ^ (((x>>2)&7)<<4));
                S[tl] = MFMA16(*(const bf16x8*)((const char*)f_xi + off), qb, S[tl]);
            }
#pragma unroll
            for (int tl2 = 0; tl2 < 2; ++tl2) {
                const int il_m = tl2*16 + lr;
                const int base = il_m*2048, swz = (il_m&7)<<4;
                fcA[c*2 + tl2][0] = lds_ld8(f_ix, base + ((w*128      + hg*16) ^ swz));
                fcA[c*2 + tl2][1] = lds_ld8(f_ix, base + ((w*128 + 64 + hg*16) ^ swz));
            }
        }
        __syncthreads();
    }

    // ================= softmax (P stays in registers) =================
    float m_l = -INFINITY;
#pragma unroll
    for (int tl = 0; tl < 4; ++tl)
#pragma unroll
        for (int r = 0; r < 4; ++r) m_l = fmaxf(m_l, S[tl][r]);
    m_l = fmaxf(m_l, __shfl_xor(m_l, 16));
    m_l = fmaxf(m_l, __shfl_xor(m_l, 32));
    if (L < 16) red_m[w*16 + L] = m_l;
    __syncthreads();
    float m_g = -INFINITY;
#pragma unroll
    for (int k = 0; k < 16; ++k) m_g = fmaxf(m_g, red_m[k*16 + lr]);
    float zl = 0.f;
#pragma unroll
    for (int tl = 0; tl < 4; ++tl)
#pragma unroll
        for (int r = 0; r < 4; ++r) {
            S[tl][r] = __expf(S[tl][r] - m_g);
            zl += S[tl][r];
        }
    // P -> per-wave 2KB scratch [l][x_local] (f_xi region; logits done)
#pragma unroll
    for (int tl = 0; tl < 4; ++tl) {
        bf16x4 pv; pv[0]=f2bf(S[tl][0]); pv[1]=f2bf(S[tl][1]); pv[2]=f2bf(S[tl][2]); pv[3]=f2bf(S[tl][3]);
        *(bf16x4*)((char*)f_xi + w*2048 + lr*128 + ((tl*32 + hg*8) ^ ((lr&7)<<4))) = pv;
    }
    zl += __shfl_xor(zl, 16);
    zl += __shfl_xor(zl, 32);
    if (L < 16) red_z[w*16 + L] = zl;
    {   // Wv -> LDS [d][i] bf16 (same phase; read much later)
        const int d = t >> 4, i4 = (t & 15) * 4;
        bf16x4 wb; wb[0]=f2bf(wv4[0]); wb[1]=f2bf(wv4[1]); wb[2]=f2bf(wv4[2]); wb[3]=f2bf(wv4[3]);
        *(bf16x4*)((char*)wv_ld + d*128 + ((i4*2) ^ ((d&7)<<4))) = wb;
    }
    __syncthreads();
    float Zg = 0.f;
#pragma unroll
    for (int k = 0; k < 16; ++k) Zg += red_z[k*16 + lr];
    const float rz = 1.f / Zg;
    const bf16x8 pb0 = *(const bf16x8*)((const char*)f_xi + w*2048 + lr*128 + ((     hg*16) ^ ((lr&7)<<4)));
    const bf16x8 pb1 = *(const bf16x8*)((const char*)f_xi + w*2048 + lr*128 + ((64 + hg*16) ^ ((lr&7)<<4)));

    // ================= fc = f @ P from registers =================
#pragma unroll
    for (int ct = 0; ct < 4; ++ct) {
        f32x4 acc = (f32x4){0.f, 0.f, 0.f, 0.f};
        acc = MFMA16(fcA[ct][0], pb0, acc);
        acc = MFMA16(fcA[ct][1], pb1, acc);
        *(f32x4*)((char*)f_ix + w*4096 + ct*1024 + L*16) = acc;   // dump partials
    }
    __syncthreads();

    // ================= reduce + normalize + epilogue =================
    if (w < 4) {   // wave w reduces i-tile w over 16 wave-partials
        f32x4 sum = (f32x4){0.f, 0.f, 0.f, 0.f};
#pragma unroll
        for (int wp = 0; wp < 16; ++wp)
            sum += *(const f32x4*)((const char*)f_ix + wp*4096 + w*1024 + L*16);
        bf16x4 fb;
#pragma unroll
        for (int r = 0; r < 4; ++r) fb[r] = f2bf(sum[r] * rz);
        *(bf16x4*)((char*)fcn_ld + lr*128 + ((w*32 + hg*8) ^ ((lr&7)<<4))) = fb;
    }
    __syncthreads();
    if (w < 4) {   // tok[d][l] = Wv @ fcn + bv; wave w owns d-tile w
        f32x4 acc = (f32x4){0.f, 0.f, 0.f, 0.f};
        const int d_m = w*16 + lr;
#pragma unroll
        for (int ks = 0; ks < 2; ++ks) {
            const bf16x8 a = lds_ld8(wv_ld, d_m*128 + ((ks*64 + hg*16) ^ ((d_m&7)<<4)));
            const bf16x8 b = lds_ld8(fcn_ld, lr*128 + ((ks*64 + hg*16) ^ ((lr&7)<<4)));
            acc = MFMA16(a, b, acc);
        }
#pragma unroll
        for (int r = 0; r < 4; ++r) {
            const int d = w*16 + hg*4 + r;
            out1[((size_t)n*1024 + h*64 + d)*16 + lr] = acc[r] + bv[h*64 + d];
        }
    }
}

// ---------------------------------------------------------------------------
extern "C" void kernel_launch(void* const* d_in, const int* in_sizes, int n_in,
                              void* d_out, int out_size, void* d_ws, size_t ws_size,
                              hipStream_t stream) {
    const float* feature = (const float*)d_in[0];
    const float* token   = (const float*)d_in[1];
    const float* Wq      = (const float*)d_in[2];
    const float* bq      = (const float*)d_in[3];
    const float* Wk      = (const float*)d_in[4];
    // d_in[5] = bk: provably unused (constant along softmax axis)
    const float* Wv      = (const float*)d_in[6];
    const float* bv      = (const float*)d_in[7];

    float* out0 = (float*)d_out;                      // feature passthrough
    float* out1 = out0 + (size_t)NB * 1024 * HW;      // tok [n][c][l]

    short* Wq_bf = (short*)d_ws;                               // 2 MB
    short* tok_t = Wq_bf + (size_t)1024 * 1024;                // 1 MB
    short* Wk_t  = tok_t + (size_t)NB * 16 * 1024;             // 128 KB
    short* qk_bf = Wk_t + (size_t)NHEAD * 64 * 64;             // 1 MB
    float* qkb   = (float*)(qk_bf + (size_t)NB * NHEAD * 1024);// 4 KB

    prep_kernel   <<<dim3(1072), 256, 0, stream>>>(Wq, token, Wk, bq, Wq_bf, tok_t, Wk_t, qkb);
    queryqk_kernel<<<dim3(NB * NHEAD), 256, 0, stream>>>(Wq_bf, tok_t, Wk_t, qkb, qk_bf);
    attn_kernel   <<<dim3(NB * NHEAD), 1024, 0, stream>>>(feature, qk_bf, Wv, bv, out0, out1);
}